// Round 4
// baseline (836.074 us; speedup 1.0000x reference)
//
#include <hip/hip_runtime.h>
#include <hip/hip_bf16.h>
#include <math.h>

#define LN_EPS 1e-5f
#define EPSA 1e-8f
#define SCALE 0.0625f   // 256^-0.5

typedef __attribute__((ext_vector_type(8))) short short8;
typedef __attribute__((ext_vector_type(4))) short short4_t;
typedef __attribute__((ext_vector_type(4))) float f32x4;

__device__ inline unsigned short f2bf(float f) {
    union { float f; unsigned int u; } v; v.f = f;
    unsigned int r = v.u + 0x7fffu + ((v.u >> 16) & 1u);   // RNE
    return (unsigned short)(r >> 16);
}
__device__ inline float bf2f(unsigned short h) {
    union { unsigned int u; float f; } v; v.u = ((unsigned int)h) << 16;
    return v.f;
}
__device__ inline float sigmoidf_(float x) { return 1.0f / (1.0f + expf(-x)); }

// ---------- K1: pack Wcb[512][256] bf16 : rows 0-255 = Wk, 256-511 = Wv ----------
__global__ __launch_bounds__(256) void pack_wb(const float* __restrict__ Wk,
                                               const float* __restrict__ Wv,
                                               __hip_bfloat16* __restrict__ Wcb) {
    int idx = blockIdx.x * 256 + threadIdx.x;   // n*256 + k
    int n = idx >> 8, k = idx & 255;
    float v = (n < 256) ? Wk[n*256 + k] : Wv[(n-256)*256 + k];
    Wcb[idx] = __float2bfloat16(v);
}

// ---------- K2: fused LN-stats + LN + MFMA GEMM -> k,v (bf16) ----------
// BM=64, full K=256 in one pass; x read exactly once.
// LDS swizzle: addr = FULL_LINEAR ^ ((row&7)<<4), applied identically on
// write and read (round-3 bug: read XORed before adding ks*64).
__global__ __launch_bounds__(256) void gemm_kv_fused(const float* __restrict__ x,
                                                     const float* __restrict__ nx_g,
                                                     const float* __restrict__ nx_b,
                                                     const __hip_bfloat16* __restrict__ Wcb,
                                                     __hip_bfloat16* __restrict__ kp,
                                                     __hip_bfloat16* __restrict__ vp) {
    __shared__ short As[64*256];   // bf16 bits, swizzled
    __shared__ float gb[512];      // nx_g | nx_b
    const int t = threadIdx.x;
    const int row0 = blockIdx.x * 64;
    const int r = t >> 2, q = t & 3;

    // phase A: 4 threads per row, 64 elems each
    float4 xr[16];
    const float* xrow = x + (size_t)(row0 + r) * 256 + q*4;
    #pragma unroll
    for (int j = 0; j < 16; ++j) xr[j] = *(const float4*)(xrow + j*16);
    gb[t] = nx_g[t]; gb[t+256] = nx_b[t];

    float s = 0.f, s2 = 0.f;
    #pragma unroll
    for (int j = 0; j < 16; ++j) {
        s  += xr[j].x + xr[j].y + xr[j].z + xr[j].w;
        s2 += xr[j].x*xr[j].x + xr[j].y*xr[j].y + xr[j].z*xr[j].z + xr[j].w*xr[j].w;
    }
    s  += __shfl_xor(s, 1);  s2 += __shfl_xor(s2, 1);
    s  += __shfl_xor(s, 2);  s2 += __shfl_xor(s2, 2);
    float m = s * (1.0f/256.0f);
    float var = s2 * (1.0f/256.0f) - m*m;
    float rstd = rsqrtf(var + LN_EPS);
    __syncthreads();   // gb ready

    #pragma unroll
    for (int j = 0; j < 16; ++j) {
        int c = q*4 + j*16;
        float4 g = *(const float4*)&gb[c];
        float4 bb = *(const float4*)&gb[256 + c];
        short4_t o;
        o[0] = (short)f2bf((xr[j].x - m)*rstd*g.x + bb.x);
        o[1] = (short)f2bf((xr[j].y - m)*rstd*g.y + bb.y);
        o[2] = (short)f2bf((xr[j].z - m)*rstd*g.z + bb.z);
        o[3] = (short)f2bf((xr[j].w - m)*rstd*g.w + bb.w);
        int byte = ((r << 9) + (c << 1)) ^ ((r & 7) << 4);   // full-linear XOR
        *(short4_t*)((char*)As + byte) = o;
    }
    __syncthreads();

    // phase B
    const int l = t & 63, w = t >> 6;
    const int lr = l & 15, lk = l >> 4;
    const int arow = w*16 + lr;
    short8 af[8];
    #pragma unroll
    for (int ks = 0; ks < 8; ++ks) {
        int lin = (arow << 9) + (lk << 4) + (ks << 6);       // full linear
        af[ks] = *(short8*)((char*)As + (lin ^ ((arow & 7) << 4)));
    }
    for (int c = 0; c < 8; ++c) {
        f32x4 acc[4];
        #pragma unroll
        for (int bf = 0; bf < 4; ++bf) acc[bf] = (f32x4){0.f,0.f,0.f,0.f};
        #pragma unroll
        for (int ks = 0; ks < 8; ++ks) {
            #pragma unroll
            for (int bf = 0; bf < 4; ++bf) {
                const short8 bv = *(const short8*)((const short*)Wcb +
                    ((size_t)(c*64 + bf*16 + lr))*256 + ks*32 + lk*8);
                acc[bf] = __builtin_amdgcn_mfma_f32_16x16x32_bf16(af[ks], bv, acc[bf], 0, 0, 0);
            }
        }
        __hip_bfloat16* dst = (c < 4) ? kp : vp;
        const int cb = c*64 - ((c >= 4) ? 256 : 0);
        #pragma unroll
        for (int bf = 0; bf < 4; ++bf) {
            int col = cb + bf*16 + lr;
            #pragma unroll
            for (int jj = 0; jj < 4; ++jj) {
                int row = row0 + w*16 + lk*4 + jj;
                dst[(size_t)row*256 + col] = __float2bfloat16(acc[bf][jj]);
            }
        }
    }
}

// ---------- K3: slots init ----------
__global__ __launch_bounds__(256) void slots_init(const float* __restrict__ noise,
                                                  const float* __restrict__ mu,
                                                  const float* __restrict__ logsigma,
                                                  float* __restrict__ slots) {
    int i = blockIdx.x * 256 + threadIdx.x;   // 65536
    int d = i & 255;
    slots[i] = mu[d] + expf(logsigma[d]) * noise[i];
}

// ---------- K4: LN(slots) + q projection -> q hi/lo bf16 [b][16][256] ----------
__global__ __launch_bounds__(256) void qproj(const float* __restrict__ slots,
                                             const float* __restrict__ ns_g,
                                             const float* __restrict__ ns_b,
                                             const float* __restrict__ Wq,
                                             unsigned short* __restrict__ qb) {
    int row = blockIdx.x, t = threadIdx.x;   // row = b*8 + s
    int b = row >> 3, s8 = row & 7;
    __shared__ float sn[256];
    __shared__ float red[8];
    float v = slots[row*256 + t];
    float s = v, s2 = v*v;
    for (int off = 32; off > 0; off >>= 1) {
        s  += __shfl_down(s, off);
        s2 += __shfl_down(s2, off);
    }
    if ((t & 63) == 0) { red[t>>6] = s; red[4 + (t>>6)] = s2; }
    __syncthreads();
    float S  = red[0]+red[1]+red[2]+red[3];
    float S2 = red[4]+red[5]+red[6]+red[7];
    float m = S * (1.0f/256.0f);
    float var = S2 * (1.0f/256.0f) - m*m;
    float rs = rsqrtf(var + LN_EPS);
    sn[t] = (v - m) * rs * ns_g[t] + ns_b[t];
    __syncthreads();
    float acc = 0.0f;
    const float4* wrow = (const float4*)(Wq + t*256);
    #pragma unroll 8
    for (int i = 0; i < 64; ++i) {
        float4 w = wrow[i];
        acc += w.x*sn[4*i] + w.y*sn[4*i+1] + w.z*sn[4*i+2] + w.w*sn[4*i+3];
    }
    unsigned short hh = f2bf(acc);
    unsigned short ll = f2bf(acc - bf2f(hh));
    qb[((size_t)(b*16 + s8))*256 + t]     = hh;
    qb[((size_t)(b*16 + 8 + s8))*256 + t] = ll;
}

// ---------- K5: fused MFMA QK^T + softmax(slots) + attn out + MFMA PV ----------
__global__ __launch_bounds__(256) void attn_fused(const __hip_bfloat16* __restrict__ kp,
                                                  const __hip_bfloat16* __restrict__ vp,
                                                  const unsigned short* __restrict__ qb,
                                                  float* __restrict__ attn_out,
                                                  float* __restrict__ partial) {
    __shared__ short as_[16*264];   // rows 0-7: attn hi, 8-15: attn lo (pad 8)
    __shared__ float asf[8*256];    // f32 attn for output write
    const int b = blockIdx.x >> 4, c = blockIdx.x & 15;
    const int t = threadIdx.x, l = t & 63, w = t >> 6;
    const int lr = l & 15, lk = l >> 4;
    const int n0 = c * 256;

    // q fragments: B-cols 0-7 = q_hi rows, 8-15 = q_lo rows
    short8 qf[8];
    #pragma unroll
    for (int ks = 0; ks < 8; ++ks)
        qf[ks] = *(const short8*)(qb + ((size_t)(b*16 + lr))*256 + ks*32 + lk*8);

    // QK^T: A = k-rows
    f32x4 acc[4];
    #pragma unroll
    for (int nf = 0; nf < 4; ++nf) acc[nf] = (f32x4){0.f,0.f,0.f,0.f};
    #pragma unroll
    for (int ks = 0; ks < 8; ++ks) {
        #pragma unroll
        for (int nf = 0; nf < 4; ++nf) {
            const short8 a = *(const short8*)((const short*)kp +
                ((size_t)(b*4096 + n0 + w*64 + nf*16 + lr))*256 + ks*32 + lk*8);
            acc[nf] = __builtin_amdgcn_mfma_f32_16x16x32_bf16(a, qf[ks], acc[nf], 0, 0, 0);
        }
    }

    // combine q hi/lo (cols s and s+8), scale, softmax over slots (lane bits 0-2)
    const float renorm = 1.0f / (1.0f + 8.0f*EPSA);
    #pragma unroll
    for (int nf = 0; nf < 4; ++nf) {
        #pragma unroll
        for (int jj = 0; jj < 4; ++jj) {
            float lg = acc[nf][jj];
            lg += __shfl_xor(lg, 8);
            lg *= SCALE;
            float mx = lg;
            mx = fmaxf(mx, __shfl_xor(mx, 1));
            mx = fmaxf(mx, __shfl_xor(mx, 2));
            mx = fmaxf(mx, __shfl_xor(mx, 4));
            float e = expf(lg - mx);
            float ss = e;
            ss += __shfl_xor(ss, 1);
            ss += __shfl_xor(ss, 2);
            ss += __shfl_xor(ss, 4);
            acc[nf][jj] = (e / ss + EPSA) * renorm;
        }
    }

    if (lr < 8) {
        #pragma unroll
        for (int nf = 0; nf < 4; ++nf) {
            int nl = w*64 + nf*16 + lk*4;
            float4 fa = {acc[nf][0], acc[nf][1], acc[nf][2], acc[nf][3]};
            *(float4*)&asf[lr*256 + nl] = fa;
            short4_t ah, al;
            #pragma unroll
            for (int jj = 0; jj < 4; ++jj) {
                unsigned short h = f2bf(acc[nf][jj]);
                ah[jj] = (short)h;
                al[jj] = (short)f2bf(acc[nf][jj] - bf2f(h));
            }
            *(short4_t*)&as_[lr*264 + nl]       = ah;
            *(short4_t*)&as_[(8 + lr)*264 + nl] = al;
        }
    }
    __syncthreads();

    // coalesced attn output
    {
        int slot = t >> 5, nn = (t & 31) * 8;
        float4 f0 = *(float4*)&asf[slot*256 + nn];
        float4 f1 = *(float4*)&asf[slot*256 + nn + 4];
        float* dstp = attn_out + ((size_t)(b*8 + slot))*4096 + n0 + nn;
        *(float4*)dstp = f0;
        *(float4*)(dstp + 4) = f1;
    }

    // PV: A = attn (hi rows 0-7, lo rows 8-15), B = v^T gathered; wave owns 64 d
    f32x4 pacc[4];
    #pragma unroll
    for (int df = 0; df < 4; ++df) pacc[df] = (f32x4){0.f,0.f,0.f,0.f};
    #pragma unroll
    for (int ks = 0; ks < 8; ++ks) {
        const short8 a = *(const short8*)&as_[lr*264 + ks*32 + lk*8];
        #pragma unroll
        for (int df = 0; df < 4; ++df) {
            short8 bv;
            #pragma unroll
            for (int j = 0; j < 8; ++j)
                bv[j] = ((const short*)vp)[((size_t)(b*4096 + n0 + ks*32 + lk*8 + j))*256
                                           + w*64 + df*16 + lr];
            pacc[df] = __builtin_amdgcn_mfma_f32_16x16x32_bf16(a, bv, pacc[df], 0, 0, 0);
        }
    }
    // combine attn hi (rows 0-7, lanes<32) with lo (rows 8-15, lanes>=32)
    #pragma unroll
    for (int df = 0; df < 4; ++df) {
        #pragma unroll
        for (int jj = 0; jj < 4; ++jj) {
            float v = pacc[df][jj];
            float vo = __shfl_xor(v, 32);
            if (l < 32) {
                int slot = lk*4 + jj;   // lk in {0,1} -> slots 0-7
                partial[((size_t)((b*16 + c)*8 + slot))*256 + w*64 + df*16 + lr] = v + vo;
            }
        }
    }
}

// ---------- K6: reduce partials + GRU + LN + MLP + residual ----------
__global__ __launch_bounds__(256) void gru_mlp(const float* __restrict__ partial,
                                               const float* __restrict__ slots,
                                               const float* __restrict__ W_ih,
                                               const float* __restrict__ W_hh,
                                               const float* __restrict__ b_ih,
                                               const float* __restrict__ b_hh,
                                               const float* __restrict__ mlp_g,
                                               const float* __restrict__ mlp_b,
                                               const float* __restrict__ W1,
                                               const float* __restrict__ b1,
                                               const float* __restrict__ W2,
                                               const float* __restrict__ b2,
                                               float* __restrict__ slots_out,
                                               float* __restrict__ out_slots,
                                               int last) {
    int rrow = blockIdx.x, t = threadIdx.x;
    int b = rrow >> 3, k = rrow & 7;
    __shared__ float u_s[256], h_s[256];
    __shared__ float hn[256], m1[512];
    __shared__ float red[8];
    float u = 0.0f;
    #pragma unroll
    for (int ch = 0; ch < 16; ++ch)
        u += partial[(((size_t)(b*16 + ch)*8 + k)*256) + t];
    u_s[t] = u;
    h_s[t] = slots[rrow*256 + t];
    __syncthreads();

    float gi_r = b_ih[t], gi_z = b_ih[256 + t], gi_n = b_ih[512 + t];
    float gh_r = b_hh[t], gh_z = b_hh[256 + t], gh_n = b_hh[512 + t];
    const float4* wir = (const float4*)(W_ih + (size_t)t*256);
    const float4* wiz = (const float4*)(W_ih + (size_t)(256 + t)*256);
    const float4* win = (const float4*)(W_ih + (size_t)(512 + t)*256);
    const float4* whr = (const float4*)(W_hh + (size_t)t*256);
    const float4* whz = (const float4*)(W_hh + (size_t)(256 + t)*256);
    const float4* whn = (const float4*)(W_hh + (size_t)(512 + t)*256);
    #pragma unroll 4
    for (int i = 0; i < 64; ++i) {
        float u0 = u_s[4*i], u1 = u_s[4*i+1], u2 = u_s[4*i+2], u3 = u_s[4*i+3];
        float h0 = h_s[4*i], h1 = h_s[4*i+1], h2 = h_s[4*i+2], h3 = h_s[4*i+3];
        float4 wv;
        wv = wir[i]; gi_r += wv.x*u0 + wv.y*u1 + wv.z*u2 + wv.w*u3;
        wv = wiz[i]; gi_z += wv.x*u0 + wv.y*u1 + wv.z*u2 + wv.w*u3;
        wv = win[i]; gi_n += wv.x*u0 + wv.y*u1 + wv.z*u2 + wv.w*u3;
        wv = whr[i]; gh_r += wv.x*h0 + wv.y*h1 + wv.z*h2 + wv.w*h3;
        wv = whz[i]; gh_z += wv.x*h0 + wv.y*h1 + wv.z*h2 + wv.w*h3;
        wv = whn[i]; gh_n += wv.x*h0 + wv.y*h1 + wv.z*h2 + wv.w*h3;
    }
    float rg = sigmoidf_(gi_r + gh_r);
    float zg = sigmoidf_(gi_z + gh_z);
    float ng = tanhf(gi_n + rg * gh_n);
    float hval = (1.0f - zg)*ng + zg*h_s[t];

    // LN(hval) across the block
    float s = hval, s2 = hval*hval;
    for (int off = 32; off > 0; off >>= 1) {
        s  += __shfl_down(s, off);
        s2 += __shfl_down(s2, off);
    }
    __syncthreads();
    if ((t & 63) == 0) { red[t>>6] = s; red[4 + (t>>6)] = s2; }
    __syncthreads();
    float S  = red[0]+red[1]+red[2]+red[3];
    float S2 = red[4]+red[5]+red[6]+red[7];
    float m = S * (1.0f/256.0f);
    float var = S2 * (1.0f/256.0f) - m*m;
    float rs = rsqrtf(var + LN_EPS);
    hn[t] = (hval - m) * rs * mlp_g[t] + mlp_b[t];
    __syncthreads();

    #pragma unroll
    for (int jj = 0; jj < 2; ++jj) {
        int j = t + jj*256;
        float acc = b1[j];
        const float4* wv = (const float4*)(W1 + (size_t)j*256);
        #pragma unroll 8
        for (int i = 0; i < 64; ++i) {
            float4 ww = wv[i];
            acc += ww.x*hn[4*i] + ww.y*hn[4*i+1] + ww.z*hn[4*i+2] + ww.w*hn[4*i+3];
        }
        m1[j] = 0.5f * acc * (1.0f + erff(acc * 0.70710678118654752f));
    }
    __syncthreads();

    float acc = b2[t];
    const float4* w2 = (const float4*)(W2 + (size_t)t*512);
    #pragma unroll 8
    for (int i = 0; i < 128; ++i) {
        float4 ww = w2[i];
        acc += ww.x*m1[4*i] + ww.y*m1[4*i+1] + ww.z*m1[4*i+2] + ww.w*m1[4*i+3];
    }
    float res = hval + acc;
    slots_out[rrow*256 + t] = res;
    if (last) out_slots[rrow*256 + t] = res;
}

// ---------- launch ----------
extern "C" void kernel_launch(void* const* d_in, const int* in_sizes, int n_in,
                              void* d_out, int out_size, void* d_ws, size_t ws_size,
                              hipStream_t stream) {
    const float* x        = (const float*)d_in[0];
    const float* noise    = (const float*)d_in[1];
    const float* nx_g     = (const float*)d_in[2];
    const float* nx_b     = (const float*)d_in[3];
    const float* ns_g     = (const float*)d_in[4];
    const float* ns_b     = (const float*)d_in[5];
    const float* mu       = (const float*)d_in[6];
    const float* logsigma = (const float*)d_in[7];
    const float* Wq       = (const float*)d_in[8];
    const float* Wk       = (const float*)d_in[9];
    const float* Wv       = (const float*)d_in[10];
    const float* W_ih     = (const float*)d_in[11];
    const float* W_hh     = (const float*)d_in[12];
    const float* b_ih     = (const float*)d_in[13];
    const float* b_hh     = (const float*)d_in[14];
    const float* mlp_g    = (const float*)d_in[15];
    const float* mlp_b    = (const float*)d_in[16];
    const float* W1       = (const float*)d_in[17];
    const float* b1       = (const float*)d_in[18];
    const float* W2       = (const float*)d_in[19];
    const float* b2       = (const float*)d_in[20];

    float* out_slots = (float*)d_out;            // [32][8][256]
    float* out_attn  = (float*)d_out + 65536;    // [32][8][4096]

    char* ws = (char*)d_ws;
    __hip_bfloat16* Wcb = (__hip_bfloat16*)ws;                   // 256 KB
    unsigned short* qb  = (unsigned short*)(Wcb + 131072);       // 256 KB
    __hip_bfloat16* kp  = (__hip_bfloat16*)(qb + 131072);        // 67 MB
    __hip_bfloat16* vp  = kp + (size_t)33554432;                 // 67 MB
    float* slots  = (float*)(vp + (size_t)33554432);             // 256 KB
    float* partial= slots + 65536;                               // 4 MB

    pack_wb<<<512, 256, 0, stream>>>(Wk, Wv, Wcb);
    gemm_kv_fused<<<2048, 256, 0, stream>>>(x, nx_g, nx_b, Wcb, kp, vp);
    slots_init<<<256, 256, 0, stream>>>(noise, mu, logsigma, slots);

    for (int it = 0; it < 3; ++it) {
        qproj<<<256, 256, 0, stream>>>(slots, ns_g, ns_b, Wq, qb);
        attn_fused<<<512, 256, 0, stream>>>(kp, vp, qb, out_attn, partial);
        gru_mlp<<<256, 256, 0, stream>>>(partial, slots, W_ih, W_hh, b_ih, b_hh,
                                         mlp_g, mlp_b, W1, b1, W2, b2,
                                         slots, out_slots, it == 2);
    }
}